// Round 19
// baseline (118.415 us; speedup 1.0000x reference)
//
#include <hip/hip_runtime.h>
#include <hip/hip_bf16.h>
#include <cstdint>

typedef __attribute__((ext_vector_type(4))) float f32x4;
typedef __attribute__((ext_vector_type(2))) long long2_t;

#define DIM 256
#define TINV 10.0f
#define EXP2C 14.426950408889634f   // TINV * log2(e)
#define BM 128
#define BN 128
#define BK 64
#define NT 64                        // N/BN
#define T_TILES 2080                 // NT*(NT+1)/2

// Kernel 1: row-normalize y (f32) -> fp8 e4m3, PAIR-INTERLEAVED (R16 format):
// within each 64B row-block, 8B-unit u lands at byte 16*(u&3)+8*(u>>2).
__global__ void nt_normalize(const float* __restrict__ y, uint8_t* __restrict__ ynq,
                             int N) {
    int tid = threadIdx.x;
    int wave = tid >> 6, lane = tid & 63;
    int row = blockIdx.x * 4 + wave;
    float4 v = ((const float4*)(y + (size_t)row * DIM))[lane];
    float ss = v.x * v.x + v.y * v.y + v.z * v.z + v.w * v.w;
#pragma unroll
    for (int off = 1; off < 64; off <<= 1) ss += __shfl_xor(ss, off);
    float inv = 1.0f / fmaxf(sqrtf(ss), 1e-8f);
    int w = __builtin_amdgcn_cvt_pk_fp8_f32(v.x * inv, v.y * inv, 0, false);
    w = __builtin_amdgcn_cvt_pk_fp8_f32(v.z * inv, v.w * inv, w, true);
    int u_row = lane >> 1;
    int addr = (u_row >> 3) * 64 + (((u_row & 7) & 3) << 4) + (((u_row & 7) >> 2) << 3)
               + ((lane & 1) << 2);
    *(int*)(ynq + (size_t)row * DIM + addr) = w;
}

// Kernel 2: fp8 sim-GEMM (R16 body; B-frags upgraded to ds_read_b128) +
// SPIN-FREE fused reduce: each strip s has exactly 64 contributing tiles;
// after P stores each tile fences and increments its strips' counters; the
// increment that returns 63 makes THIS block the last contributor -- all data
// already visible, reduce strip s immediately (no waiting). A second counter
// fires the final 64-float sum on the 64th strip completion. No spin loops
// anywhere (R13/R17/R18: spin loops collapse VGPR to 32 and spill acc).
__launch_bounds__(512, 8)
__global__ void nt_gemm_red(const uint8_t* __restrict__ ynq, float* __restrict__ P,
                            float* __restrict__ posterm, float* __restrict__ stripsum,
                            unsigned* __restrict__ scnt, unsigned* __restrict__ cnt2,
                            float* __restrict__ out, int N) {
    const int nt = NT;
    const int T = T_TILES;
    // bijective XCD-chunked swizzle (m204)
    int orig = blockIdx.x;
    int q = T >> 3, r = T & 7;
    int xcd = orig & 7, loc = orig >> 3;
    int t = (xcd < r ? xcd * (q + 1) : r * (q + 1) + (xcd - r) * q) + loc;
    // triangular index -> (by, bx), by <= bx (from bottom-right corner)
    int s = T - 1 - t;
    float f = sqrtf(8.0f * (float)s + 1.0f);
    int j = (int)((f - 1.0f) * 0.5f);
    while ((j + 1) * (j + 2) / 2 <= s) ++j;
    while (j * (j + 1) / 2 > s) --j;
    int k = s - j * (j + 1) / 2;
    int by = nt - 1 - j, bx = nt - 1 - k;

    __shared__ __align__(16) uint8_t As[BM * BK];    // 8 KB
    __shared__ __align__(16) uint8_t Bs[BN * BK];    // 8 KB
    __shared__ float rowpart[4][BM];                 // 2 KB (reused by reduce)
    __shared__ float colpart[2][BN];                 // 1 KB (reused by reduce)
    __shared__ int sh_red0, sh_red1, sh_fin;

    int r0 = by * BM, c0 = bx * BN;
    int tid = threadIdx.x;
    int wave = tid >> 6, lane = tid & 63;
    int wr = wave >> 2, wc = wave & 3;
    int l16 = lane & 15, lg = lane >> 4;

    int srow = tid >> 2, scc = tid & 3;
    int sgc = scc ^ (srow & 3);
    int slot16 = (lg ^ (l16 & 3)) * 16;

    int arow[4], brow[2];
#pragma unroll
    for (int m = 0; m < 4; ++m) arow[m] = (wr * 64 + m * 16 + l16) * BK;
#pragma unroll
    for (int n = 0; n < 2; ++n) brow[n] = (wc * 32 + n * 16 + l16) * BK;

    f32x4 acc[4][2] = {};

    for (int k0 = 0; k0 < DIM; k0 += BK) {
        if (k0) __syncthreads();
        {
            const uint8_t* srcA = ynq + (size_t)(r0 + srow) * DIM + k0 + sgc * 16;
            __builtin_amdgcn_global_load_lds(
                (const __attribute__((address_space(1))) uint32_t*)srcA,
                (__attribute__((address_space(3))) uint32_t*)(As + wave * 1024), 16, 0, 0);
            const uint8_t* srcB = ynq + (size_t)(c0 + srow) * DIM + k0 + sgc * 16;
            __builtin_amdgcn_global_load_lds(
                (const __attribute__((address_space(1))) uint32_t*)srcB,
                (__attribute__((address_space(3))) uint32_t*)(Bs + wave * 1024), 16, 0, 0);
        }
        __syncthreads();

        long2_t a2[4], b2v[2];
#pragma unroll
        for (int m = 0; m < 4; ++m)
            a2[m] = *(const long2_t*)(As + arow[m] + slot16);
#pragma unroll
        for (int n = 0; n < 2; ++n)
            b2v[n] = *(const long2_t*)(Bs + brow[n] + slot16);
#pragma unroll
        for (int kk = 0; kk < 2; ++kk) {
#pragma unroll
            for (int m = 0; m < 4; ++m) {
                long am = kk ? a2[m].y : a2[m].x;
#pragma unroll
                for (int n = 0; n < 2; ++n)
                    acc[m][n] = __builtin_amdgcn_mfma_f32_16x16x32_fp8_fp8(
                        am, kk ? b2v[n].y : b2v[n].x, acc[m][n], 0, 0, 0);
            }
        }
    }

    // Epilogue (R16 verbatim). C/D layout (m89): col=lane&15, row=lg*4+reg.
    bool diag = (by == bx);
    float colacc0 = 0.0f, colacc1 = 0.0f;
    float rp[16];
#pragma unroll
    for (int m = 0; m < 4; ++m) {
#pragma unroll
        for (int r2 = 0; r2 < 4; ++r2) {
            int grow = r0 + wr * 64 + m * 16 + lg * 4 + r2;
            float s0, s1;
            {
                float S = acc[m][0][r2];
                float e = __builtin_amdgcn_exp2f(S * EXP2C);
                if (diag) {
                    int gcol = c0 + wc * 32 + l16;
                    if (gcol == grow) e = 0.0f;
                    if (gcol == (grow ^ 1)) posterm[grow] = -S * TINV;
                }
                s0 = e; colacc0 += e;
            }
            {
                float S = acc[m][1][r2];
                float e = __builtin_amdgcn_exp2f(S * EXP2C);
                if (diag) {
                    int gcol = c0 + wc * 32 + 16 + l16;
                    if (gcol == grow) e = 0.0f;
                    if (gcol == (grow ^ 1)) posterm[grow] = -S * TINV;
                }
                s1 = e; colacc1 += e;
            }
            rp[m * 4 + r2] = s0 + s1;
        }
    }
    int b0 = l16 & 1, b1 = (l16 >> 1) & 1, b2_ = (l16 >> 2) & 1, b3 = (l16 >> 3) & 1;
    float t8[8];
#pragma unroll
    for (int i = 0; i < 8; ++i) {
        float send = b0 ? rp[2 * i] : rp[2 * i + 1];
        float keep = b0 ? rp[2 * i + 1] : rp[2 * i];
        t8[i] = keep + __shfl_xor(send, 1);
    }
    float t4[4];
#pragma unroll
    for (int i = 0; i < 4; ++i) {
        float send = b1 ? t8[2 * i] : t8[2 * i + 1];
        float keep = b1 ? t8[2 * i + 1] : t8[2 * i];
        t4[i] = keep + __shfl_xor(send, 2);
    }
    float t2[2];
#pragma unroll
    for (int i = 0; i < 2; ++i) {
        float send = b2_ ? t4[2 * i] : t4[2 * i + 1];
        float keep = b2_ ? t4[2 * i + 1] : t4[2 * i];
        t2[i] = keep + __shfl_xor(send, 4);
    }
    {
        float send = b3 ? t2[0] : t2[1];
        float keep = b3 ? t2[1] : t2[0];
        float rsum = keep + __shfl_xor(send, 8);
        int row_w = ((l16 >> 2) & 3) * 16 + lg * 4 + (l16 & 3);
        rowpart[wc][wr * 64 + row_w] = rsum;
    }
    colacc0 += __shfl_xor(colacc0, 16); colacc0 += __shfl_xor(colacc0, 32);
    colacc1 += __shfl_xor(colacc1, 16); colacc1 += __shfl_xor(colacc1, 32);
    if (!diag && lane < 16) {
        colpart[wr][wc * 32 + lane] = colacc0;
        colpart[wr][wc * 32 + 16 + lane] = colacc1;
    }
    __syncthreads();
    if (tid < BM) {
        P[(size_t)bx * N + r0 + tid] =
            rowpart[0][tid] + rowpart[1][tid] + rowpart[2][tid] + rowpart[3][tid];
    } else if (tid < 2 * BM && !diag) {
        int lcol = tid - BM;
        P[(size_t)by * N + c0 + lcol] = colpart[0][lcol] + colpart[1][lcol];
    }

    // ---- Spin-free fused reduce: last contributor of each strip reduces it ----
    __syncthreads();                              // drains all P stores (vmcnt 0)
    if (tid == 0) {
        __threadfence();                          // release this block's P data
        unsigned ra = atomicAdd(&scnt[by], 1u);
        sh_red0 = (ra == 63u) ? by : -1;
        sh_red1 = -1;
        if (!diag) {
            unsigned rb = atomicAdd(&scnt[bx], 1u);
            if (rb == 63u) { if (sh_red0 < 0) sh_red0 = bx; else sh_red1 = bx; }
        }
    }
    __syncthreads();
    int nred = (sh_red0 >= 0) + (sh_red1 >= 0);
    if (nred == 0) return;                        // block-uniform exit
    __threadfence();                              // acquire: all 64 contributions

    for (int it = 0; it < nred; ++it) {
        int sidx = it == 0 ? sh_red0 : sh_red1;
        // 512 threads: part p = tid>>7 sums 16 slots for row (tid&127).
        int p = tid >> 7, rr = tid & 127;
        float partial = 0.0f;
#pragma unroll
        for (int jj = 0; jj < 16; ++jj)
            partial += P[(size_t)(p * 16 + jj) * N + sidx * 128 + rr];
        __syncthreads();                          // rowpart safe to reuse
        rowpart[p][rr] = partial;
        __syncthreads();
        float v = 0.0f;
        if (tid < 128) {
            float ssum = rowpart[0][tid] + rowpart[1][tid] + rowpart[2][tid]
                         + rowpart[3][tid];
            v = posterm[sidx * 128 + tid] + logf(ssum);
        }
#pragma unroll
        for (int off = 1; off < 64; off <<= 1) v += __shfl_xor(v, off);
        if (lane == 0 && tid < 128) colpart[0][wave] = v;
        __syncthreads();
        if (tid == 0) {
            stripsum[sidx] = colpart[0][0] + colpart[0][1];
            __threadfence();                      // release strip partial
            unsigned rc = atomicAdd(cnt2, 1u);
            sh_fin = (rc == 63u) ? 1 : 0;
        }
        __syncthreads();
        if (sh_fin && wave == 0) {                // 64th strip: finalize
            __threadfence();                      // acquire all strip partials
            float w = __hip_atomic_load(&stripsum[lane], __ATOMIC_RELAXED,
                                        __HIP_MEMORY_SCOPE_AGENT);
#pragma unroll
            for (int off = 1; off < 64; off <<= 1) w += __shfl_xor(w, off);
            if (lane == 0) out[0] = w / (float)N;
        }
    }
}

extern "C" void kernel_launch(void* const* d_in, const int* in_sizes, int n_in,
                              void* d_out, int out_size, void* d_ws, size_t ws_size,
                              hipStream_t stream) {
    const float* y = (const float*)d_in[0];
    int N = in_sizes[0] / DIM;                 // 8192
    uint8_t* ynq = (uint8_t*)d_ws;             // 2 MB (pair-interleaved fp8)
    float* posterm = (float*)((char*)d_ws + (size_t)N * DIM);   // 32 KB
    float* P = posterm + N;                    // 64*N f32 = 2 MB
    float* stripsum = P + (size_t)NT * N;      // 64 f32
    unsigned* scnt = (unsigned*)(stripsum + NT);   // 64 strip counters
    unsigned* cnt2 = scnt + NT;                // 1 finalize counter
    float* out = (float*)d_out;

    hipMemsetAsync(scnt, 0, (NT + 1) * sizeof(unsigned), stream);  // per-call reset
    nt_normalize<<<N / 4, 256, 0, stream>>>(y, ynq, N);
    nt_gemm_red<<<T_TILES, 512, 0, stream>>>(ynq, P, posterm, stripsum,
                                             scnt, cnt2, out, N);
}

// Round 21
// 34.205 us; speedup vs baseline: 3.4619x; 3.4619x over previous
//
#include <hip/hip_runtime.h>
#include <hip/hip_bf16.h>
#include <cstdint>

typedef __attribute__((ext_vector_type(4))) float f32x4;
typedef __attribute__((ext_vector_type(2))) long long2_t;

#define DIM 256
#define TINV 10.0f
// TINV * log2(e): exp(S/T) == exp2(S * EXP2C)
#define EXP2C 14.426950408889634f
#define BM 128
#define BN 128
#define BK 64
#define NSLOT 64   // N/BN, compile-time for full unroll in reduce
#define NRED 32    // reduce blocks (N/(64*4)); power of two for ticket mask

// Kernel 1: row-normalize y (f32) -> fp8 e4m3, PAIR-INTERLEAVED (R16 format):
// within each 64B row-block, 8B-unit u lands at byte 16*(u&3)+8*(u>>2), so
// units {g, g+4} (= one lane's kk0/kk1 MFMA pieces) form one 16B chunk.
__global__ void nt_normalize(const float* __restrict__ y, uint8_t* __restrict__ ynq,
                             int N) {
    int tid = threadIdx.x;
    int wave = tid >> 6, lane = tid & 63;
    int row = blockIdx.x * 4 + wave;
    float4 v = ((const float4*)(y + (size_t)row * DIM))[lane];
    float ss = v.x * v.x + v.y * v.y + v.z * v.z + v.w * v.w;
#pragma unroll
    for (int off = 1; off < 64; off <<= 1) ss += __shfl_xor(ss, off);
    float inv = 1.0f / fmaxf(sqrtf(ss), 1e-8f);
    int w = __builtin_amdgcn_cvt_pk_fp8_f32(v.x * inv, v.y * inv, 0, false);
    w = __builtin_amdgcn_cvt_pk_fp8_f32(v.z * inv, v.w * inv, w, true);
    int u_row = lane >> 1;
    int addr = (u_row >> 3) * 64 + (((u_row & 7) & 3) << 4) + (((u_row & 7) >> 2) << 3)
               + ((lane & 1) << 2);
    *(int*)(ynq + (size_t)row * DIM + addr) = w;
}

// Kernel 2: fp8 sim-GEMM + exp + partials + pos capture (R16 structure).
// 128x128 tile, 8 waves (2Mx4N, wave out 64x32), BK=64 K-loop, 4 blocks/CU,
// triangular grid (by<=bx), single-writer P scheme, no output atomics.
// Pair-interleaved ynq: A AND B fragments each load as ONE ds_read_b128
// (lo 8B = kk0, hi 8B = kk1) at slot lg^(l16&3) — conflict-free (R16/R19
// bank audit). LDS instructions: 6 per wave-K-tile.
__launch_bounds__(512, 8)
__global__ void nt_gemm(const uint8_t* __restrict__ ynq, float* __restrict__ P,
                        float* __restrict__ posterm, int N) {
    const int nt = N / BN;                      // 64
    const int T = nt * (nt + 1) / 2;            // 2080
    // bijective XCD-chunked swizzle (m204)
    int orig = blockIdx.x;
    int q = T >> 3, r = T & 7;
    int xcd = orig & 7, loc = orig >> 3;
    int t = (xcd < r ? xcd * (q + 1) : r * (q + 1) + (xcd - r) * q) + loc;
    // triangular index -> (by, bx), by <= bx (count from bottom-right corner)
    int s = T - 1 - t;
    float f = sqrtf(8.0f * (float)s + 1.0f);
    int j = (int)((f - 1.0f) * 0.5f);
    while ((j + 1) * (j + 2) / 2 <= s) ++j;
    while (j * (j + 1) / 2 > s) --j;
    int k = s - j * (j + 1) / 2;
    int by = nt - 1 - j, bx = nt - 1 - k;

    __shared__ __align__(16) uint8_t As[BM * BK];    // 8 KB (fp8 K-tile)
    __shared__ __align__(16) uint8_t Bs[BN * BK];    // 8 KB
    __shared__ float rowpart[4][BM];                 // 2 KB [wc][row-in-tile]
    __shared__ float colpart[2][BN];                 // 1 KB [wr][col-in-tile]

    int r0 = by * BM, c0 = bx * BN;
    int tid = threadIdx.x;
    int wave = tid >> 6, lane = tid & 63;
    int wr = wave >> 2, wc = wave & 3;               // 2 x 4 wave grid
    int l16 = lane & 15, lg = lane >> 4;

    // Staging: LDS 16B slot (row, cc) holds permuted-global chunk cc ^ (row&3).
    int srow = tid >> 2, scc = tid & 3;
    int sgc = scc ^ (srow & 3);

    // Reader: pair lg (lane's kk0+kk1 data) stored at slot lg ^ (row&3);
    // row&3 == l16&3 for every fragment row.
    int slot16 = (lg ^ (l16 & 3)) * 16;              // per-lane constant byte offset

    int arow[4], brow[2];
#pragma unroll
    for (int m = 0; m < 4; ++m) arow[m] = (wr * 64 + m * 16 + l16) * BK;
#pragma unroll
    for (int n = 0; n < 2; ++n) brow[n] = (wc * 32 + n * 16 + l16) * BK;

    f32x4 acc[4][2] = {};

    for (int k0 = 0; k0 < DIM; k0 += BK) {
        if (k0) __syncthreads();   // protect previous iter's LDS reads
        {
            const uint8_t* srcA = ynq + (size_t)(r0 + srow) * DIM + k0 + sgc * 16;
            __builtin_amdgcn_global_load_lds(
                (const __attribute__((address_space(1))) uint32_t*)srcA,
                (__attribute__((address_space(3))) uint32_t*)(As + wave * 1024), 16, 0, 0);
            const uint8_t* srcB = ynq + (size_t)(c0 + srow) * DIM + k0 + sgc * 16;
            __builtin_amdgcn_global_load_lds(
                (const __attribute__((address_space(1))) uint32_t*)srcB,
                (__attribute__((address_space(3))) uint32_t*)(Bs + wave * 1024), 16, 0, 0);
        }
        __syncthreads();   // drain; 3 co-resident blocks + 8 waves hide the stall

        // A and B: ds_read_b128 each (conflict-free), both kk pieces per read.
        long2_t a2[4], b2v[2];
#pragma unroll
        for (int m = 0; m < 4; ++m)
            a2[m] = *(const long2_t*)(As + arow[m] + slot16);
#pragma unroll
        for (int n = 0; n < 2; ++n)
            b2v[n] = *(const long2_t*)(Bs + brow[n] + slot16);
#pragma unroll
        for (int kk = 0; kk < 2; ++kk) {
#pragma unroll
            for (int m = 0; m < 4; ++m) {
                long am = kk ? a2[m].y : a2[m].x;
#pragma unroll
                for (int n = 0; n < 2; ++n)
                    acc[m][n] = __builtin_amdgcn_mfma_f32_16x16x32_fp8_fp8(
                        am, kk ? b2v[n].y : b2v[n].x, acc[m][n], 0, 0, 0);
            }
        }
    }

    // Epilogue. C/D layout (m89): col = lane&15, row = lg*4 + reg (within 16x16).
    bool diag = (by == bx);
    float colacc0 = 0.0f, colacc1 = 0.0f;
    float rp[16];
#pragma unroll
    for (int m = 0; m < 4; ++m) {
#pragma unroll
        for (int r2 = 0; r2 < 4; ++r2) {
            int grow = r0 + wr * 64 + m * 16 + lg * 4 + r2;
            float s0, s1;
            {
                float S = acc[m][0][r2];
                float e = __builtin_amdgcn_exp2f(S * EXP2C);
                if (diag) {
                    int gcol = c0 + wc * 32 + l16;
                    if (gcol == grow) e = 0.0f;
                    if (gcol == (grow ^ 1)) posterm[grow] = -S * TINV;
                }
                s0 = e; colacc0 += e;
            }
            {
                float S = acc[m][1][r2];
                float e = __builtin_amdgcn_exp2f(S * EXP2C);
                if (diag) {
                    int gcol = c0 + wc * 32 + 16 + l16;
                    if (gcol == grow) e = 0.0f;
                    if (gcol == (grow ^ 1)) posterm[grow] = -S * TINV;
                }
                s1 = e; colacc1 += e;
            }
            rp[m * 4 + r2] = s0 + s1;
        }
    }
    // Butterfly reduce-scatter over the 4 l16 bits: 15 shfl; lane l16 ends
    // holding the complete row-sum for rid = l16.
    int b0 = l16 & 1, b1 = (l16 >> 1) & 1, b2_ = (l16 >> 2) & 1, b3 = (l16 >> 3) & 1;
    float t8[8];
#pragma unroll
    for (int i = 0; i < 8; ++i) {
        float send = b0 ? rp[2 * i] : rp[2 * i + 1];
        float keep = b0 ? rp[2 * i + 1] : rp[2 * i];
        t8[i] = keep + __shfl_xor(send, 1);
    }
    float t4[4];
#pragma unroll
    for (int i = 0; i < 4; ++i) {
        float send = b1 ? t8[2 * i] : t8[2 * i + 1];
        float keep = b1 ? t8[2 * i + 1] : t8[2 * i];
        t4[i] = keep + __shfl_xor(send, 2);
    }
    float t2[2];
#pragma unroll
    for (int i = 0; i < 2; ++i) {
        float send = b2_ ? t4[2 * i] : t4[2 * i + 1];
        float keep = b2_ ? t4[2 * i + 1] : t4[2 * i];
        t2[i] = keep + __shfl_xor(send, 4);
    }
    {
        float send = b3 ? t2[0] : t2[1];
        float keep = b3 ? t2[1] : t2[0];
        float rsum = keep + __shfl_xor(send, 8);
        int row_w = ((l16 >> 2) & 3) * 16 + lg * 4 + (l16 & 3);   // rid = l16
        rowpart[wc][wr * 64 + row_w] = rsum;                       // 1 write/lane
    }
    // col partials: xor 16/32 reduces over this wave's 64 rows (lg groups)
    colacc0 += __shfl_xor(colacc0, 16); colacc0 += __shfl_xor(colacc0, 32);
    colacc1 += __shfl_xor(colacc1, 16); colacc1 += __shfl_xor(colacc1, 32);
    if (!diag && lane < 16) {
        colpart[wr][wc * 32 + lane] = colacc0;
        colpart[wr][wc * 32 + 16 + lane] = colacc1;
    }
    __syncthreads();
    // Single-writer stores: threads 0..127 -> row sums, 128..255 -> col sums.
    if (tid < BM) {
        P[(size_t)bx * N + r0 + tid] =
            rowpart[0][tid] + rowpart[1][tid] + rowpart[2][tid] + rowpart[3][tid];
    } else if (tid < 2 * BM && !diag) {
        int lcol = tid - BM;
        P[(size_t)by * N + c0 + lcol] = colpart[0][lcol] + colpart[1][lcol];
    }
}

// Kernel 3: reduce + fused final via last-block ticket (R16 verbatim,
// twice-validated). 32 blocks x 1 wave; each lane owns 4 consecutive rows,
// reading float4 per P slot (wave reads 1 KB contiguous per slot).
__global__ void nt_reduce_final(const float* __restrict__ P,
                                const float* __restrict__ posterm,
                                float* __restrict__ blockpart,
                                unsigned* __restrict__ cnt,
                                float* __restrict__ out, int N) {
    int lane = threadIdx.x;                     // 64 threads = 1 wave
    int gid = blockIdx.x * 64 + lane;           // float4 index over rows
    f32x4 ps = {0.0f, 0.0f, 0.0f, 0.0f};
#pragma unroll
    for (int jj = 0; jj < NSLOT; ++jj)
        ps += ((const f32x4*)(P + (size_t)jj * N))[gid];
    f32x4 pt = ((const f32x4*)posterm)[gid];
    float v = (pt[0] + logf(ps[0])) + (pt[1] + logf(ps[1])) +
              (pt[2] + logf(ps[2])) + (pt[3] + logf(ps[3]));
#pragma unroll
    for (int off = 1; off < 64; off <<= 1) v += __shfl_xor(v, off);
    unsigned ticket = 0;
    if (lane == 0) {
        blockpart[blockIdx.x] = v;
        __threadfence();                        // release: partial visible
        ticket = atomicAdd(cnt, 1u);
    }
    ticket = __shfl(ticket, 0);
    if ((ticket & (NRED - 1u)) == NRED - 1u) {  // last arrival of this call
        __threadfence();                        // acquire
        float w = (lane < NRED)
                      ? __hip_atomic_load(&blockpart[lane], __ATOMIC_RELAXED,
                                          __HIP_MEMORY_SCOPE_AGENT)
                      : 0.0f;
#pragma unroll
        for (int off = 1; off < 64; off <<= 1) w += __shfl_xor(w, off);
        if (lane == 0) out[0] = w / (float)N;
    }
}

extern "C" void kernel_launch(void* const* d_in, const int* in_sizes, int n_in,
                              void* d_out, int out_size, void* d_ws, size_t ws_size,
                              hipStream_t stream) {
    const float* y = (const float*)d_in[0];
    int N = in_sizes[0] / DIM;                 // 8192
    int nt = N / BN;                           // 64
    uint8_t* ynq = (uint8_t*)d_ws;             // 2 MB (pair-interleaved fp8)
    float* posterm = (float*)((char*)d_ws + (size_t)N * DIM);   // 32 KB
    float* P = posterm + N;                    // nt*N f32 = 2 MB
    float* blockpart = P + (size_t)nt * N;     // NRED f32
    unsigned* cnt = (unsigned*)(blockpart + NRED);   // ticket counter
    float* out = (float*)d_out;

    nt_normalize<<<N / 4, 256, 0, stream>>>(y, ynq, N);
    int T = nt * (nt + 1) / 2;                 // 2080 blocks, no dead work
    nt_gemm<<<T, 512, 0, stream>>>(ynq, P, posterm, N);
    nt_reduce_final<<<NRED, 64, 0, stream>>>(P, posterm, blockpart, cnt, out, N);
}